// Round 6
// baseline (171.126 us; speedup 1.0000x reference)
//
#include <hip/hip_runtime.h>
#include <hip/hip_bf16.h>
#include <stdint.h>

// Problem constants: T=512, B=32, I=512, H=512
#define T_DIM 512
#define B_DIM 32
#define K_DIM 512     // I
#define H_DIM 512
#define N_PAD 2048    // 4*H: gates packed h*4+g, g=3 is a zero pad column
#define M_DIM 16384   // T*B

typedef __bf16 bf16_t;
typedef bf16_t bf16x8 __attribute__((ext_vector_type(8)));
typedef float floatx4 __attribute__((ext_vector_type(4)));

#define LOG2E 1.442695041f     // 1/ln(2)
#define TWO_LOG2E 2.885390082f

// ---------- fp32 -> bf16 (RNE), 8 elems/thread, both inputs fused ----------
// W_ih is permuted AND padded: Wb row h*4+g <- original row g*512+h (g<3),
// row h*4+3 <- zeros. GEMM's N axis is then natively gate-packed with a pad
// column, so the fp16 epilogue writes are dense full lines (R4 lesson:
// sub-line scatter triples WRITE_SIZE via partial-line RMW at HBM).
__device__ __forceinline__ unsigned int f2bf_bits(float f) {
  uint32_t u = __builtin_bit_cast(uint32_t, f);
  u += 0x7FFFu + ((u >> 16) & 1u);
  return u >> 16;
}

__global__ void convert_both_kernel(const float* __restrict__ x,
                                    unsigned short* __restrict__ xb,
                                    const float* __restrict__ W,
                                    unsigned short* __restrict__ Wb) {
  int bid = blockIdx.x;
  if (bid < 4096) {           // x: 8388608 elems, identity convert
    int i = (bid * 256 + threadIdx.x) * 8;
    const float4* p = (const float4*)(x + i);
    float4 f0 = p[0];
    float4 f1 = p[1];
    uint4 v;
    v.x = f2bf_bits(f0.x) | (f2bf_bits(f0.y) << 16);
    v.y = f2bf_bits(f0.z) | (f2bf_bits(f0.w) << 16);
    v.z = f2bf_bits(f1.x) | (f2bf_bits(f1.y) << 16);
    v.w = f2bf_bits(f1.z) | (f2bf_bits(f1.w) << 16);
    *(uint4*)(xb + i) = v;
  } else {                    // Wb: 2048 rows x 512, permuted+padded
    int i = ((bid - 4096) * 256 + threadIdx.x) * 8;  // output index
    int orow = i >> 9;        // packed row h*4+g
    int k = i & 511;
    int g = orow & 3;
    int h = orow >> 2;
    uint4 v;
    if (g < 3) {
      const float4* p = (const float4*)(W + ((g << 9) + h) * 512 + k);
      float4 f0 = p[0];
      float4 f1 = p[1];
      v.x = f2bf_bits(f0.x) | (f2bf_bits(f0.y) << 16);
      v.y = f2bf_bits(f0.z) | (f2bf_bits(f0.w) << 16);
      v.z = f2bf_bits(f1.x) | (f2bf_bits(f1.y) << 16);
      v.w = f2bf_bits(f1.z) | (f2bf_bits(f1.w) << 16);
    } else {
      v = uint4{0, 0, 0, 0};
    }
    *(uint4*)(Wb + i) = v;
  }
}

// ---------- bf16 GEMM: NT, 128x128 tile, BK=64, XOR-swizzled LDS ----------
// A: M x K bf16 (x), Bm: N_PAD x K bf16 (W_ih packed h*4+g, g=3 zero).
// C: M x N_PAD fp16, pre-scaled for the scan (g in {0,1}: -log2e for
// sigmoid-via-exp2; g==2: +2*log2e for tanh; g==3: zero pad).
__global__ __launch_bounds__(256) void gemm_bf16_kernel(
    const unsigned short* __restrict__ A, const unsigned short* __restrict__ Bm,
    _Float16* __restrict__ C) {
  __shared__ bf16_t smem[16384];  // [0..8191] A-tile 128x64, [8192..] B-tile
  const int tid = threadIdx.x;
  const int lane = tid & 63;
  const int w = tid >> 6;
  const int tileM = blockIdx.x * 128;
  const int tileN = blockIdx.y * 128;
  const int waveM = w & 1;
  const int waveN = w >> 1;
  const int lm = lane & 15;
  const int lg = lane >> 4;       // 0..3 k-chunk group

  floatx4 acc[4][4] = {};

  for (int k0 = 0; k0 < K_DIM; k0 += 64) {
#pragma unroll
    for (int j = 0; j < 4; ++j) {
      // slot s in [0,1024): 16B chunks; row = s>>3, cpos = s&7
      int s = j * 256 + tid;
      int row = s >> 3;
      int cpos = s & 7;
      int kc = cpos ^ (row & 7);  // source chunk under swizzle
      bf16_t* la = smem + (j * 256 + w * 64) * 8;
      const unsigned short* ga = A + (size_t)(tileM + row) * K_DIM + k0 + kc * 8;
      __builtin_amdgcn_global_load_lds(
          (const __attribute__((address_space(1))) unsigned int*)ga,
          (__attribute__((address_space(3))) unsigned int*)la, 16, 0, 0);
      bf16_t* lb = smem + 8192 + (j * 256 + w * 64) * 8;
      const unsigned short* gb = Bm + (size_t)(tileN + row) * K_DIM + k0 + kc * 8;
      __builtin_amdgcn_global_load_lds(
          (const __attribute__((address_space(1))) unsigned int*)gb,
          (__attribute__((address_space(3))) unsigned int*)lb, 16, 0, 0);
    }
    __syncthreads();

#pragma unroll
    for (int ks = 0; ks < 2; ++ks) {
      bf16x8 af[4], bfg[4];
#pragma unroll
      for (int i = 0; i < 4; ++i) {
        int row = waveM * 64 + i * 16 + lm;
        int c = ks * 4 + lg;
        af[i] = *(const bf16x8*)(smem + row * 64 + (c ^ (row & 7)) * 8);
      }
#pragma unroll
      for (int j = 0; j < 4; ++j) {
        int row = waveN * 64 + j * 16 + lm;
        int c = ks * 4 + lg;
        bfg[j] = *(const bf16x8*)(smem + 8192 + row * 64 + (c ^ (row & 7)) * 8);
      }
#pragma unroll
      for (int i = 0; i < 4; ++i)
#pragma unroll
        for (int j = 0; j < 4; ++j)
          acc[i][j] = __builtin_amdgcn_mfma_f32_16x16x32_bf16(af[i], bfg[j],
                                                              acc[i][j], 0, 0, 0);
    }
    __syncthreads();
  }

  // Epilogue: C/D layout col=lane&15, row=(lane>>4)*4+reg (m89/m91 verified).
  // 16 consecutive lanes write 16 consecutive fp16 (32B); the 4 j-cols per
  // row cover a dense 128B span -> full lines collectively.
  const int row0 = tileM + waveM * 64 + (lane >> 4) * 4;
  const int col0 = tileN + waveN * 64 + lm;
#pragma unroll
  for (int j = 0; j < 4; ++j) {
    const int col = col0 + j * 16;
    const float scl = ((col & 3) == 2) ? TWO_LOG2E : -LOG2E;  // pad col: acc==0
#pragma unroll
    for (int i = 0; i < 4; ++i)
#pragma unroll
      for (int r = 0; r < 4; ++r)
        C[(size_t)(row0 + i * 16 + r) * N_PAD + col] = (_Float16)(scl * acc[i][j][r]);
  }
}

// ---------- diagonal GRU scan ----------
// gx fp16 gate-packed: quad (gr',gz',gn',pad) at gx[m*2048 + h*4 ..], m=t*B+b,
// pre-scaled (gr',gz' by -log2e; gn' by 2*log2e). One dwordx2 load per step.
// sigmoid(x) = rcp(1 + exp2(-log2e*x)); tanh(y) = 1 - 2*rcp(exp2(2*log2e*y)+1).
// Depth-16 register prefetch; per-step asm memory clobber pins the distance
// (R3 lesson: otherwise the compiler rotates loads to just-in-time and the
// scan runs at one exposed memory round-trip per step).
__device__ __forceinline__ float unpack_lo(uint32_t w16) {
  return (float)__builtin_bit_cast(_Float16, (unsigned short)(w16 & 0xffff));
}
__device__ __forceinline__ float unpack_hi(uint32_t w16) {
  return (float)__builtin_bit_cast(_Float16, (unsigned short)(w16 >> 16));
}

__global__ __launch_bounds__(64) void indgru_scan_kernel(
    const _Float16* __restrict__ gx, const float* __restrict__ h0,
    const float* __restrict__ w_hh, float* __restrict__ out,
    float* __restrict__ hlast) {
  const int idx = blockIdx.x * 64 + threadIdx.x;  // 0..16383
  const int b = idx >> 9;
  const int h = idx & (H_DIM - 1);
  const float wr = -LOG2E * w_hh[h];
  const float wz = -LOG2E * w_hh[H_DIM + h];
  const float wn = TWO_LOG2E * w_hh[2 * H_DIM + h];
  float hv = h0[idx];

  const _Float16* base = gx + ((size_t)b * H_DIM + h) * 4;  // t-stride 65536 fp16
  float* outp = out + (size_t)b * H_DIM + h;                // t-stride 16384 fp32

  constexpr int D = 16;
  uint2 pq[D];
#pragma unroll
  for (int t = 0; t < D; ++t)
    pq[t] = *(const uint2*)(base + (size_t)t * (B_DIM * N_PAD));

  for (int t0 = 0; t0 < T_DIM - D; t0 += D) {
#pragma unroll
    for (int s = 0; s < D; ++s) {
      const int t = t0 + s;
      uint2 q = pq[s];
      pq[s] = *(const uint2*)(base + (size_t)(t + D) * (B_DIM * N_PAD));
      asm volatile("" ::: "memory");  // pin prefetch distance
      float gr = unpack_lo(q.x);
      float gz = unpack_hi(q.x);
      float gn = unpack_lo(q.y);
      float ar = fmaf(wr, hv, gr);
      float az = fmaf(wz, hv, gz);
      float t1 = wn * hv;
      float er = __builtin_amdgcn_exp2f(ar);
      float ez = __builtin_amdgcn_exp2f(az);
      float r = __builtin_amdgcn_rcpf(1.0f + er);
      float z = __builtin_amdgcn_rcpf(1.0f + ez);
      float en = __builtin_amdgcn_exp2f(fmaf(r, t1, gn));
      float u = __builtin_amdgcn_rcpf(1.0f + en);
      float n = fmaf(-2.0f, u, 1.0f);
      float zh = z * hv;
      float omz = 1.0f - z;
      hv = fmaf(n, omz, zh);
      outp[(size_t)t * (B_DIM * H_DIM)] = hv;
    }
  }
#pragma unroll
  for (int s = 0; s < D; ++s) {
    const int t = T_DIM - D + s;
    uint2 q = pq[s];
    float gr = unpack_lo(q.x);
    float gz = unpack_hi(q.x);
    float gn = unpack_lo(q.y);
    float ar = fmaf(wr, hv, gr);
    float az = fmaf(wz, hv, gz);
    float t1 = wn * hv;
    float er = __builtin_amdgcn_exp2f(ar);
    float ez = __builtin_amdgcn_exp2f(az);
    float r = __builtin_amdgcn_rcpf(1.0f + er);
    float z = __builtin_amdgcn_rcpf(1.0f + ez);
    float en = __builtin_amdgcn_exp2f(fmaf(r, t1, gn));
    float u = __builtin_amdgcn_rcpf(1.0f + en);
    float n = fmaf(-2.0f, u, 1.0f);
    float zh = z * hv;
    float omz = 1.0f - z;
    hv = fmaf(n, omz, zh);
    outp[(size_t)t * (B_DIM * H_DIM)] = hv;
  }
  hlast[idx] = hv;
}

extern "C" void kernel_launch(void* const* d_in, const int* in_sizes, int n_in,
                              void* d_out, int out_size, void* d_ws, size_t ws_size,
                              hipStream_t stream) {
  const float* x    = (const float*)d_in[0];   // (T,B,I)  = 8388608
  const float* h0   = (const float*)d_in[1];   // (B,H)    = 16384
  const float* W_ih = (const float*)d_in[2];   // (3H,I)   = 786432
  const float* w_hh = (const float*)d_in[3];   // (3,H)    = 1536

  float* out = (float*)d_out;                          // (T,B,H)
  float* hlast = out + (size_t)T_DIM * B_DIM * H_DIM;  // (1,B,H)

  // workspace: xb(bf16) 16 MB | Wb(bf16 2048x512) 2 MB | gx(fp16 packed) 67 MB
  char* ws = (char*)d_ws;
  unsigned short* xb = (unsigned short*)ws;
  unsigned short* Wb = (unsigned short*)(ws + 16777216);
  _Float16* gx = (_Float16*)(ws + 16777216 + 2097152);

  convert_both_kernel<<<4608, 256, 0, stream>>>(x, xb, W_ih, Wb);

  dim3 grid(M_DIM / 128, N_PAD / 128);  // 128 x 16
  gemm_bf16_kernel<<<grid, 256, 0, stream>>>(xb, Wb, gx);

  indgru_scan_kernel<<<256, 64, 0, stream>>>(gx, h0, w_hh, out, hlast);
}

// Round 7
// 160.671 us; speedup vs baseline: 1.0651x; 1.0651x over previous
//
#include <hip/hip_runtime.h>
#include <hip/hip_bf16.h>
#include <stdint.h>

// Problem constants: T=512, B=32, I=512, H=512
#define T_DIM 512
#define B_DIM 32
#define K_DIM 512     // I
#define H_DIM 512
#define N_DIM 1536    // 3*H, gate-packed in h-pairs: n = (h>>1)*6 + (h&1)*3 + g
#define M_DIM 16384   // T*B

typedef __bf16 bf16_t;
typedef bf16_t bf16x8 __attribute__((ext_vector_type(8)));
typedef float floatx4 __attribute__((ext_vector_type(4)));

#define LOG2E 1.442695041f     // 1/ln(2)
#define TWO_LOG2E 2.885390082f

// ---------- fp32 -> bf16 (RNE), 8 elems/thread, both inputs fused ----------
// W_ih rows permuted to h-pair gate packing: Wb row (h>>1)*6 + (h&1)*3 + g
// <- original row g*512+h. GEMM's N axis is then natively packed so that
// each h's 3 gates start at byte (h>>1)*12 + (h&1)*4 in a C row -> the scan
// loads one 4B-aligned dwordx2 per step. (R4 lesson: epilogue must write
// full 64B lines; R6 lesson: 32B half-line stores re-amplify to fp32 size.)
__device__ __forceinline__ unsigned int f2bf_bits(float f) {
  uint32_t u = __builtin_bit_cast(uint32_t, f);
  u += 0x7FFFu + ((u >> 16) & 1u);
  return u >> 16;
}

__global__ void convert_both_kernel(const float* __restrict__ x,
                                    unsigned short* __restrict__ xb,
                                    const float* __restrict__ W,
                                    unsigned short* __restrict__ Wb) {
  int bid = blockIdx.x;
  const float* src;
  unsigned short* dst;
  int i;
  if (bid < 4096) {           // x: 8388608 elems, identity convert
    i = (bid * 256 + threadIdx.x) * 8;
    src = x + i;
    dst = xb + i;
  } else {                    // Wb: 1536 rows x 512, h-pair permuted
    i = ((bid - 4096) * 256 + threadIdx.x) * 8;
    int n = i >> 9;           // packed row
    int k = i & 511;
    int p6 = n / 6;
    int sub = n - p6 * 6;
    int hodd = (sub >= 3) ? 1 : 0;
    int g = sub - hodd * 3;
    int h = p6 * 2 + hodd;
    src = W + ((g << 9) + h) * 512 + k;
    dst = Wb + i;
  }
  const float4* p = (const float4*)src;
  float4 f0 = p[0];
  float4 f1 = p[1];
  uint4 v;
  v.x = f2bf_bits(f0.x) | (f2bf_bits(f0.y) << 16);
  v.y = f2bf_bits(f0.z) | (f2bf_bits(f0.w) << 16);
  v.z = f2bf_bits(f1.x) | (f2bf_bits(f1.y) << 16);
  v.w = f2bf_bits(f1.z) | (f2bf_bits(f1.w) << 16);
  *(uint4*)dst = v;
}

// ---------- bf16 GEMM: NT, 128x128 tile, BK=64, XOR-swizzled LDS ----------
// A: M x K bf16 (x), Bm: N x K bf16 (W_ih, h-pair packed). C: M x N fp16,
// pre-scaled (gates r,z by -log2e for sigmoid-via-exp2; gate n by +2*log2e
// for tanh). Epilogue: per-wave LDS transpose -> dwordx2 full-line stores.
__global__ __launch_bounds__(256) void gemm_bf16_kernel(
    const unsigned short* __restrict__ A, const unsigned short* __restrict__ Bm,
    _Float16* __restrict__ C) {
  __shared__ bf16_t smem[16384];  // [0..8191] A-tile 128x64, [8192..] B-tile
  const int tid = threadIdx.x;
  const int lane = tid & 63;
  const int w = tid >> 6;
  const int tileM = blockIdx.x * 128;
  const int tileN = blockIdx.y * 128;
  const int waveM = w & 1;
  const int waveN = w >> 1;
  const int lm = lane & 15;
  const int lg = lane >> 4;       // 0..3 k-chunk group

  floatx4 acc[4][4] = {};

  for (int k0 = 0; k0 < K_DIM; k0 += 64) {
#pragma unroll
    for (int j = 0; j < 4; ++j) {
      // slot s in [0,1024): 16B chunks; row = s>>3, cpos = s&7
      int s = j * 256 + tid;
      int row = s >> 3;
      int cpos = s & 7;
      int kc = cpos ^ (row & 7);  // source chunk under swizzle
      bf16_t* la = smem + (j * 256 + w * 64) * 8;
      const unsigned short* ga = A + (size_t)(tileM + row) * K_DIM + k0 + kc * 8;
      __builtin_amdgcn_global_load_lds(
          (const __attribute__((address_space(1))) unsigned int*)ga,
          (__attribute__((address_space(3))) unsigned int*)la, 16, 0, 0);
      bf16_t* lb = smem + 8192 + (j * 256 + w * 64) * 8;
      const unsigned short* gb = Bm + (size_t)(tileN + row) * K_DIM + k0 + kc * 8;
      __builtin_amdgcn_global_load_lds(
          (const __attribute__((address_space(1))) unsigned int*)gb,
          (__attribute__((address_space(3))) unsigned int*)lb, 16, 0, 0);
    }
    __syncthreads();

#pragma unroll
    for (int ks = 0; ks < 2; ++ks) {
      bf16x8 af[4], bfg[4];
#pragma unroll
      for (int i = 0; i < 4; ++i) {
        int row = waveM * 64 + i * 16 + lm;
        int c = ks * 4 + lg;
        af[i] = *(const bf16x8*)(smem + row * 64 + (c ^ (row & 7)) * 8);
      }
#pragma unroll
      for (int j = 0; j < 4; ++j) {
        int row = waveN * 64 + j * 16 + lm;
        int c = ks * 4 + lg;
        bfg[j] = *(const bf16x8*)(smem + 8192 + row * 64 + (c ^ (row & 7)) * 8);
      }
#pragma unroll
      for (int i = 0; i < 4; ++i)
#pragma unroll
        for (int j = 0; j < 4; ++j)
          acc[i][j] = __builtin_amdgcn_mfma_f32_16x16x32_bf16(af[i], bfg[j],
                                                              acc[i][j], 0, 0, 0);
    }
    __syncthreads();  // also guarantees smem reusable for the epilogue
  }

  // Epilogue. MFMA C/D layout: col=lane&15 (+16j), row=(lane>>4)*4+reg (+16i).
  // Scale per gate: packed col c -> sub=c%6, gate n iff sub%3==2.
  // Per-wave private 8KB LDS region (64x64 fp16) -> read back 4-col quads ->
  // 16 lanes x 8B = 128B contiguous global stores (full lines).
  _Float16* ep = (_Float16*)smem + w * 4096;
#pragma unroll
  for (int j = 0; j < 4; ++j) {
    const int cl = lm + j * 16;               // local col 0..63
    const int sub = (tileN + waveN * 64 + cl) % 6;
    const float scl = (sub == 2 || sub == 5) ? TWO_LOG2E : -LOG2E;
#pragma unroll
    for (int i = 0; i < 4; ++i)
#pragma unroll
      for (int r = 0; r < 4; ++r) {
        int rl = (lane >> 4) * 4 + r + 16 * i; // local row 0..63
        ep[rl * 64 + cl] = (_Float16)(scl * acc[i][j][r]);
      }
  }
  // Region is wave-private: DS ops within a wave are ordered; no barrier.
  const int q = lm;            // col quad 0..15 (4 fp16 each)
  const int rgrp = lane >> 4;  // 0..3
  const size_t crow0 = (size_t)(tileM + waveM * 64);
  const int ccol = tileN + waveN * 64 + q * 4;
#pragma unroll
  for (int k = 0; k < 16; ++k) {
    int rl = rgrp + 4 * k;
    uint2 v = *(const uint2*)(ep + rl * 64 + q * 4);
    *(uint2*)(C + (crow0 + rl) * N_DIM + ccol) = v;
  }
}

// ---------- diagonal GRU scan ----------
// gx fp16 h-pair packed: gates (gr',gz',gn') of (m,h) start at fp16 index
// m*1536 + (h>>1)*6 + (h&1)*3 -> byte (h>>1)*12 + (h&1)*4 (4B aligned).
// One dwordx2 load per step; h-parity 64-bit funnel shift unpacks 3 fp16.
// Pre-scaled (gr',gz' by -log2e; gn' by 2*log2e):
// sigmoid(x)=rcp(1+exp2(-log2e*x)); tanh(y)=1-2*rcp(exp2(2*log2e*y)+1).
// Depth-16 register prefetch; per-step asm memory clobber pins the distance
// (R3 lesson: otherwise loads rotate to just-in-time -> one exposed memory
// round-trip per step).
__global__ __launch_bounds__(64) void indgru_scan_kernel(
    const _Float16* __restrict__ gx, const float* __restrict__ h0,
    const float* __restrict__ w_hh, float* __restrict__ out,
    float* __restrict__ hlast) {
  const int idx = blockIdx.x * 64 + threadIdx.x;  // 0..16383
  const int b = idx >> 9;
  const int h = idx & (H_DIM - 1);
  const float wr = -LOG2E * w_hh[h];
  const float wz = -LOG2E * w_hh[H_DIM + h];
  const float wn = TWO_LOG2E * w_hh[2 * H_DIM + h];
  const int sh = (h & 1) << 4;  // funnel shift: 0 or 16 bits
  float hv = h0[idx];

  // byte-exact base: fp16 index m*1536 + (h>>1)*6, then +4B if h odd
  const char* base = (const char*)(gx + (size_t)b * N_DIM + (h >> 1) * 6) + ((h & 1) << 2);
  float* outp = out + (size_t)b * H_DIM + h;  // t-stride 16384 fp32

  constexpr int D = 16;
  constexpr size_t TSTRIDE = (size_t)B_DIM * N_DIM * sizeof(_Float16);  // 98304 B
  uint2 pq[D];
#pragma unroll
  for (int t = 0; t < D; ++t)
    pq[t] = *(const uint2*)(base + (size_t)t * TSTRIDE);

  auto cvt16 = [](uint32_t bits) {
    return (float)__builtin_bit_cast(_Float16, (unsigned short)bits);
  };

  for (int t0 = 0; t0 < T_DIM - D; t0 += D) {
#pragma unroll
    for (int s = 0; s < D; ++s) {
      const int t = t0 + s;
      uint2 q = pq[s];
      pq[s] = *(const uint2*)(base + (size_t)(t + D) * TSTRIDE);
      asm volatile("" ::: "memory");  // pin prefetch distance
      uint64_t v = (((uint64_t)q.y << 32) | q.x) >> sh;
      float gr = cvt16((uint32_t)v);
      float gz = cvt16((uint32_t)(v >> 16));
      float gn = cvt16((uint32_t)(v >> 32));
      float ar = fmaf(wr, hv, gr);
      float az = fmaf(wz, hv, gz);
      float t1 = wn * hv;
      float er = __builtin_amdgcn_exp2f(ar);
      float ez = __builtin_amdgcn_exp2f(az);
      float r = __builtin_amdgcn_rcpf(1.0f + er);
      float z = __builtin_amdgcn_rcpf(1.0f + ez);
      float en = __builtin_amdgcn_exp2f(fmaf(r, t1, gn));
      float u = __builtin_amdgcn_rcpf(1.0f + en);
      float n = fmaf(-2.0f, u, 1.0f);
      float zh = z * hv;
      float omz = 1.0f - z;
      hv = fmaf(n, omz, zh);
      outp[(size_t)t * (B_DIM * H_DIM)] = hv;
    }
  }
#pragma unroll
  for (int s = 0; s < D; ++s) {
    const int t = T_DIM - D + s;
    uint2 q = pq[s];
    uint64_t v = (((uint64_t)q.y << 32) | q.x) >> sh;
    float gr = cvt16((uint32_t)v);
    float gz = cvt16((uint32_t)(v >> 16));
    float gn = cvt16((uint32_t)(v >> 32));
    float ar = fmaf(wr, hv, gr);
    float az = fmaf(wz, hv, gz);
    float t1 = wn * hv;
    float er = __builtin_amdgcn_exp2f(ar);
    float ez = __builtin_amdgcn_exp2f(az);
    float r = __builtin_amdgcn_rcpf(1.0f + er);
    float z = __builtin_amdgcn_rcpf(1.0f + ez);
    float en = __builtin_amdgcn_exp2f(fmaf(r, t1, gn));
    float u = __builtin_amdgcn_rcpf(1.0f + en);
    float n = fmaf(-2.0f, u, 1.0f);
    float zh = z * hv;
    float omz = 1.0f - z;
    hv = fmaf(n, omz, zh);
    outp[(size_t)t * (B_DIM * H_DIM)] = hv;
  }
  hlast[idx] = hv;
}

extern "C" void kernel_launch(void* const* d_in, const int* in_sizes, int n_in,
                              void* d_out, int out_size, void* d_ws, size_t ws_size,
                              hipStream_t stream) {
  const float* x    = (const float*)d_in[0];   // (T,B,I)  = 8388608
  const float* h0   = (const float*)d_in[1];   // (B,H)    = 16384
  const float* W_ih = (const float*)d_in[2];   // (3H,I)   = 786432
  const float* w_hh = (const float*)d_in[3];   // (3,H)    = 1536

  float* out = (float*)d_out;                          // (T,B,H)
  float* hlast = out + (size_t)T_DIM * B_DIM * H_DIM;  // (1,B,H)

  // workspace: xb(bf16) 16 MB | Wb(bf16 1536x512) 1.5 MB | gx(fp16) 50 MB
  char* ws = (char*)d_ws;
  unsigned short* xb = (unsigned short*)ws;
  unsigned short* Wb = (unsigned short*)(ws + 16777216);
  _Float16* gx = (_Float16*)(ws + 16777216 + 1572864);

  convert_both_kernel<<<4480, 256, 0, stream>>>(x, xb, W_ih, Wb);

  dim3 grid(M_DIM / 128, N_DIM / 128);  // 128 x 12
  gemm_bf16_kernel<<<grid, 256, 0, stream>>>(xb, Wb, gx);

  indgru_scan_kernel<<<256, 64, 0, stream>>>(gx, h0, w_hh, out, hlast);
}

// Round 8
// 149.659 us; speedup vs baseline: 1.1434x; 1.0736x over previous
//
#include <hip/hip_runtime.h>
#include <hip/hip_bf16.h>
#include <stdint.h>

// Problem constants: T=512, B=32, I=512, H=512
#define T_DIM 512
#define B_DIM 32
#define K_DIM 512     // I
#define H_DIM 512
#define N_DIM 1536    // 3*H, gate-packed in h-pairs: n = (h>>1)*6 + (h&1)*3 + g
#define M_DIM 16384   // T*B

typedef __bf16 bf16_t;
typedef bf16_t bf16x8 __attribute__((ext_vector_type(8)));
typedef float floatx4 __attribute__((ext_vector_type(4)));

#define LOG2E 1.442695041f     // 1/ln(2)
#define TWO_LOG2E 2.885390082f

// ---------- fp32 -> bf16 (RNE), 8 elems/thread, both inputs fused ----------
// W_ih rows permuted to h-pair gate packing: Wb row (h>>1)*6 + (h&1)*3 + g
// <- original row g*512+h, so each h's 3 gates start 4B-aligned in a C row
// and the scan loads one dwordx2 per step. (R4/R6 lesson: epilogue stores
// must cover full 64B lines or HBM write-amplification eats the savings.)
__device__ __forceinline__ unsigned int f2bf_bits(float f) {
  uint32_t u = __builtin_bit_cast(uint32_t, f);
  u += 0x7FFFu + ((u >> 16) & 1u);
  return u >> 16;
}

__global__ void convert_both_kernel(const float* __restrict__ x,
                                    unsigned short* __restrict__ xb,
                                    const float* __restrict__ W,
                                    unsigned short* __restrict__ Wb) {
  int bid = blockIdx.x;
  const float* src;
  unsigned short* dst;
  int i;
  if (bid < 4096) {           // x: 8388608 elems, identity convert
    i = (bid * 256 + threadIdx.x) * 8;
    src = x + i;
    dst = xb + i;
  } else {                    // Wb: 1536 rows x 512, h-pair permuted
    i = ((bid - 4096) * 256 + threadIdx.x) * 8;
    int n = i >> 9;           // packed row
    int k = i & 511;
    int p6 = n / 6;
    int sub = n - p6 * 6;
    int hodd = (sub >= 3) ? 1 : 0;
    int g = sub - hodd * 3;
    int h = p6 * 2 + hodd;
    src = W + ((g << 9) + h) * 512 + k;
    dst = Wb + i;
  }
  const float4* p = (const float4*)src;
  float4 f0 = p[0];
  float4 f1 = p[1];
  uint4 v;
  v.x = f2bf_bits(f0.x) | (f2bf_bits(f0.y) << 16);
  v.y = f2bf_bits(f0.z) | (f2bf_bits(f0.w) << 16);
  v.z = f2bf_bits(f1.x) | (f2bf_bits(f1.y) << 16);
  v.w = f2bf_bits(f1.z) | (f2bf_bits(f1.w) << 16);
  *(uint4*)dst = v;
}

// ---------- bf16 GEMM: NT, 256x128 tile, BK=64, XOR-swizzled LDS ----------
// A: M x K bf16 (x), Bm: N x K bf16 (W_ih, h-pair packed). C: M x N fp16,
// pre-scaled (gates r,z by -log2e for sigmoid-via-exp2; gate n by +2*log2e).
// 512 threads = 8 waves (4 M x 2 N), each wave 64x64 via 4x4 16x16x32 MFMAs.
// R7 lesson: 128x128 was barrier-drain bound at K=512 (8 iters/block); the
// 256-row tile halves blocks -> halves aggregate drain per MFMA.
// LDS: A 256x64 (32KB) + B 128x64 (16KB) staging; epilogue reuses 32KB as
// 8 x 4KB wave-private transpose buffers (two passes of 32 rows).
__global__ __launch_bounds__(512, 4) void gemm_bf16_kernel(
    const unsigned short* __restrict__ A, const unsigned short* __restrict__ Bm,
    _Float16* __restrict__ C) {
  __shared__ bf16_t smem[24576];  // [0..16383] A-tile 256x64, [16384..] B-tile
  const int tid = threadIdx.x;
  const int lane = tid & 63;
  const int w = tid >> 6;
  const int tileM = blockIdx.x * 256;
  const int tileN = blockIdx.y * 128;
  const int waveM = w & 3;
  const int waveN = w >> 2;
  const int lm = lane & 15;
  const int lg = lane >> 4;       // 0..3 k-chunk group

  floatx4 acc[4][4] = {};

  for (int k0 = 0; k0 < K_DIM; k0 += 64) {
    // A: 2048 16B chunks (256 rows x 8), 4 groups of 512
#pragma unroll
    for (int g = 0; g < 4; ++g) {
      int s = g * 512 + tid;
      int row = s >> 3;
      int kc = (s & 7) ^ (row & 7);  // source chunk under swizzle
      bf16_t* la = smem + (g * 512 + w * 64) * 8;
      const unsigned short* ga = A + (size_t)(tileM + row) * K_DIM + k0 + kc * 8;
      __builtin_amdgcn_global_load_lds(
          (const __attribute__((address_space(1))) unsigned int*)ga,
          (__attribute__((address_space(3))) unsigned int*)la, 16, 0, 0);
    }
    // B: 1024 chunks (128 rows x 8), 2 groups of 512
#pragma unroll
    for (int g = 0; g < 2; ++g) {
      int s = g * 512 + tid;
      int row = s >> 3;
      int kc = (s & 7) ^ (row & 7);
      bf16_t* lb = smem + 16384 + (g * 512 + w * 64) * 8;
      const unsigned short* gb = Bm + (size_t)(tileN + row) * K_DIM + k0 + kc * 8;
      __builtin_amdgcn_global_load_lds(
          (const __attribute__((address_space(1))) unsigned int*)gb,
          (__attribute__((address_space(3))) unsigned int*)lb, 16, 0, 0);
    }
    __syncthreads();

#pragma unroll
    for (int ks = 0; ks < 2; ++ks) {
      bf16x8 af[4], bfg[4];
#pragma unroll
      for (int i = 0; i < 4; ++i) {
        int row = waveM * 64 + i * 16 + lm;
        int c = ks * 4 + lg;
        af[i] = *(const bf16x8*)(smem + row * 64 + (c ^ (row & 7)) * 8);
      }
#pragma unroll
      for (int j = 0; j < 4; ++j) {
        int row = waveN * 64 + j * 16 + lm;
        int c = ks * 4 + lg;
        bfg[j] = *(const bf16x8*)(smem + 16384 + row * 64 + (c ^ (row & 7)) * 8);
      }
#pragma unroll
      for (int i = 0; i < 4; ++i)
#pragma unroll
        for (int j = 0; j < 4; ++j)
          acc[i][j] = __builtin_amdgcn_mfma_f32_16x16x32_bf16(af[i], bfg[j],
                                                              acc[i][j], 0, 0, 0);
    }
    __syncthreads();  // also guarantees smem reusable for the epilogue
  }

  // Epilogue. MFMA C/D layout: col=lane&15 (+16j), row=(lane>>4)*4+reg (+16i).
  // Two passes of 32 rows through a 4KB wave-private LDS region, read back as
  // 4-col quads -> 16 lanes x 8B = 128B contiguous stores (full lines).
  _Float16* ep = (_Float16*)smem + w * 2048;  // 32x64 fp16 per wave
  const int q = lm;            // col quad 0..15
  const int rgrp = lane >> 4;  // 0..3
  const size_t crow0 = (size_t)(tileM + waveM * 64);
  const int ccol = tileN + waveN * 64 + q * 4;
#pragma unroll
  for (int p = 0; p < 2; ++p) {
#pragma unroll
    for (int il = 0; il < 2; ++il) {
      const int i = 2 * p + il;
#pragma unroll
      for (int j = 0; j < 4; ++j) {
        const int cl = lm + j * 16;
        const int sub = (tileN + waveN * 64 + cl) % 6;
        const float scl = (sub == 2 || sub == 5) ? TWO_LOG2E : -LOG2E;
#pragma unroll
        for (int r = 0; r < 4; ++r) {
          int rl = (lane >> 4) * 4 + r + 16 * il;  // 0..31
          ep[rl * 64 + cl] = (_Float16)(scl * acc[i][j][r]);
        }
      }
    }
    // wave-private region: DS ops within a wave are ordered; no barrier
#pragma unroll
    for (int k = 0; k < 8; ++k) {
      int rl = rgrp + 4 * k;  // 0..31
      uint2 v = *(const uint2*)(ep + rl * 64 + q * 4);
      *(uint2*)(C + (crow0 + p * 32 + rl) * N_DIM + ccol) = v;
    }
  }
}

// ---------- diagonal GRU scan ----------
// gx fp16 h-pair packed: gates (gr',gz',gn') of (m,h) start at fp16 index
// m*1536 + (h>>1)*6 + (h&1)*3 -> byte (h>>1)*12 + (h&1)*4 (4B aligned).
// One dwordx2 load per step; h-parity 64-bit funnel shift unpacks 3 fp16.
// Pre-scaled (gr',gz' by -log2e; gn' by 2*log2e):
// sigmoid(x)=rcp(1+exp2(-log2e*x)); tanh(y)=1-2*rcp(exp2(2*log2e*y)+1).
// Depth-32 register prefetch; per-step asm memory clobber pins the distance
// (R3 lesson: otherwise loads rotate to just-in-time -> one exposed memory
// round-trip per step).
__global__ __launch_bounds__(64) void indgru_scan_kernel(
    const _Float16* __restrict__ gx, const float* __restrict__ h0,
    const float* __restrict__ w_hh, float* __restrict__ out,
    float* __restrict__ hlast) {
  const int idx = blockIdx.x * 64 + threadIdx.x;  // 0..16383
  const int b = idx >> 9;
  const int h = idx & (H_DIM - 1);
  const float wr = -LOG2E * w_hh[h];
  const float wz = -LOG2E * w_hh[H_DIM + h];
  const float wn = TWO_LOG2E * w_hh[2 * H_DIM + h];
  const int sh = (h & 1) << 4;  // funnel shift: 0 or 16 bits
  float hv = h0[idx];

  // byte-exact base: fp16 index m*1536 + (h>>1)*6, then +4B if h odd
  const char* base = (const char*)(gx + (size_t)b * N_DIM + (h >> 1) * 6) + ((h & 1) << 2);
  float* outp = out + (size_t)b * H_DIM + h;  // t-stride 16384 fp32

  constexpr int D = 32;
  constexpr size_t TSTRIDE = (size_t)B_DIM * N_DIM * sizeof(_Float16);  // 98304 B
  uint2 pq[D];
#pragma unroll
  for (int t = 0; t < D; ++t)
    pq[t] = *(const uint2*)(base + (size_t)t * TSTRIDE);

  auto cvt16 = [](uint32_t bits) {
    return (float)__builtin_bit_cast(_Float16, (unsigned short)bits);
  };

  for (int t0 = 0; t0 < T_DIM - D; t0 += D) {
#pragma unroll
    for (int s = 0; s < D; ++s) {
      const int t = t0 + s;
      uint2 q = pq[s];
      pq[s] = *(const uint2*)(base + (size_t)(t + D) * TSTRIDE);
      asm volatile("" ::: "memory");  // pin prefetch distance
      uint64_t v = (((uint64_t)q.y << 32) | q.x) >> sh;
      float gr = cvt16((uint32_t)v);
      float gz = cvt16((uint32_t)(v >> 16));
      float gn = cvt16((uint32_t)(v >> 32));
      float ar = fmaf(wr, hv, gr);
      float az = fmaf(wz, hv, gz);
      float t1 = wn * hv;
      float er = __builtin_amdgcn_exp2f(ar);
      float ez = __builtin_amdgcn_exp2f(az);
      float r = __builtin_amdgcn_rcpf(1.0f + er);
      float z = __builtin_amdgcn_rcpf(1.0f + ez);
      float en = __builtin_amdgcn_exp2f(fmaf(r, t1, gn));
      float u = __builtin_amdgcn_rcpf(1.0f + en);
      float n = fmaf(-2.0f, u, 1.0f);
      float zh = z * hv;
      float omz = 1.0f - z;
      hv = fmaf(n, omz, zh);
      outp[(size_t)t * (B_DIM * H_DIM)] = hv;
    }
  }
#pragma unroll
  for (int s = 0; s < D; ++s) {
    const int t = T_DIM - D + s;
    uint2 q = pq[s];
    uint64_t v = (((uint64_t)q.y << 32) | q.x) >> sh;
    float gr = cvt16((uint32_t)v);
    float gz = cvt16((uint32_t)(v >> 16));
    float gn = cvt16((uint32_t)(v >> 32));
    float ar = fmaf(wr, hv, gr);
    float az = fmaf(wz, hv, gz);
    float t1 = wn * hv;
    float er = __builtin_amdgcn_exp2f(ar);
    float ez = __builtin_amdgcn_exp2f(az);
    float r = __builtin_amdgcn_rcpf(1.0f + er);
    float z = __builtin_amdgcn_rcpf(1.0f + ez);
    float en = __builtin_amdgcn_exp2f(fmaf(r, t1, gn));
    float u = __builtin_amdgcn_rcpf(1.0f + en);
    float n = fmaf(-2.0f, u, 1.0f);
    float zh = z * hv;
    float omz = 1.0f - z;
    hv = fmaf(n, omz, zh);
    outp[(size_t)t * (B_DIM * H_DIM)] = hv;
  }
  hlast[idx] = hv;
}

extern "C" void kernel_launch(void* const* d_in, const int* in_sizes, int n_in,
                              void* d_out, int out_size, void* d_ws, size_t ws_size,
                              hipStream_t stream) {
  const float* x    = (const float*)d_in[0];   // (T,B,I)  = 8388608
  const float* h0   = (const float*)d_in[1];   // (B,H)    = 16384
  const float* W_ih = (const float*)d_in[2];   // (3H,I)   = 786432
  const float* w_hh = (const float*)d_in[3];   // (3,H)    = 1536

  float* out = (float*)d_out;                          // (T,B,H)
  float* hlast = out + (size_t)T_DIM * B_DIM * H_DIM;  // (1,B,H)

  // workspace: xb(bf16) 16 MB | Wb(bf16 1536x512) 1.5 MB | gx(fp16) 50 MB
  char* ws = (char*)d_ws;
  unsigned short* xb = (unsigned short*)ws;
  unsigned short* Wb = (unsigned short*)(ws + 16777216);
  _Float16* gx = (_Float16*)(ws + 16777216 + 1572864);

  convert_both_kernel<<<4480, 256, 0, stream>>>(x, xb, W_ih, Wb);

  dim3 grid(M_DIM / 256, N_DIM / 128);  // 64 x 12
  gemm_bf16_kernel<<<grid, 512, 0, stream>>>(xb, Wb, gx);

  indgru_scan_kernel<<<256, 64, 0, stream>>>(gx, h0, w_hh, out, hlast);
}